// Round 7
// baseline (403.141 us; speedup 1.0000x reference)
//
#include <hip/hip_runtime.h>

#define F_IN 256
#define HID  16
#define NCLS 40
#define NB   512      // nodes per bucket (dest >> 9)
#define CAP  20480    // max edges per bucket
#define SPAN 8192     // edges per bscatter block

static inline int cdiv(int a, int b) { return (a + b - 1) / b; }

typedef short bf16x8 __attribute__((ext_vector_type(8)));
typedef float f32x4  __attribute__((ext_vector_type(4)));

// ---------- bf16 helpers (top 16 bits of fp32, RNE) ----------
__device__ __forceinline__ float bf_lo(unsigned int u) { return __uint_as_float(u << 16); }
__device__ __forceinline__ float bf_hi(unsigned int u) { return __uint_as_float(u & 0xFFFF0000u); }
__device__ __forceinline__ unsigned short f2bf(float a) {
    unsigned int u = __float_as_uint(a);
    return (unsigned short)((u + 0x7FFFu + ((u >> 16) & 1u)) >> 16);
}
__device__ __forceinline__ unsigned int pack_bf(float a, float b) {
    return (unsigned int)f2bf(a) | ((unsigned int)f2bf(b) << 16);
}

// ---------- per-bucket edge counts (LDS hist -> few global atomics) ----------
__global__ void __launch_bounds__(256) bcount_kernel(const int* __restrict__ col,
                                                     int* __restrict__ bkt_cnt, int E, int K) {
    __shared__ int h[256];
    int t = threadIdx.x;
    h[t] = 0;
    __syncthreads();
    int E4 = E >> 2;
    const int4* c4 = (const int4*)col;
    for (int e = blockIdx.x * 256 + t; e < E4; e += gridDim.x * 256) {
        int4 v = c4[e];
        atomicAdd(&h[v.x >> 9], 1);
        atomicAdd(&h[v.y >> 9], 1);
        atomicAdd(&h[v.z >> 9], 1);
        atomicAdd(&h[v.w >> 9], 1);
    }
    for (int e = (E4 << 2) + blockIdx.x * 256 + t; e < E; e += gridDim.x * 256)
        atomicAdd(&h[col[e] >> 9], 1);
    __syncthreads();
    if (t < K && h[t]) atomicAdd(&bkt_cnt[t], h[t]);
}

// ---------- exclusive scan of bucket counts (K <= 256), init cursors ----------
__global__ void __launch_bounds__(256) bscan_kernel(const int* __restrict__ bkt_cnt,
                                                    int* __restrict__ bkt_off,
                                                    int* __restrict__ bkt_cur, int K) {
    __shared__ int s[256];
    int t = threadIdx.x;
    int v = (t < K) ? bkt_cnt[t] : 0;
    s[t] = v;
    __syncthreads();
    for (int off = 1; off < 256; off <<= 1) {
        int x = (t >= off) ? s[t - off] : 0;
        __syncthreads();
        s[t] += x;
        __syncthreads();
    }
    int excl = s[t] - v;
    if (t < K) { bkt_off[t] = excl; bkt_cur[t] = excl; }
    if (t == K - 1) bkt_off[K] = excl + v;
}

// ---------- bucketed scatter: runs of packed entries per (block,bucket) ----------
// entry = row | (local_dest << 17); row < 2^17, local_dest < 512
__global__ void __launch_bounds__(256) bscatter_kernel(const int* __restrict__ row,
                                                       const int* __restrict__ col,
                                                       int* __restrict__ bkt_cur,
                                                       int* __restrict__ entries, int E) {
    __shared__ int cnt[256];
    __shared__ int base[256];
    int t = threadIdx.x;
    int start = blockIdx.x * SPAN;
    int end = min(start + SPAN, E);
    cnt[t] = 0;
    __syncthreads();
    int m = end - start;
    int m4 = m >> 2;
    const int4* c4 = (const int4*)(col + start);
    for (int i = t; i < m4; i += 256) {
        int4 v = c4[i];
        atomicAdd(&cnt[v.x >> 9], 1);
        atomicAdd(&cnt[v.y >> 9], 1);
        atomicAdd(&cnt[v.z >> 9], 1);
        atomicAdd(&cnt[v.w >> 9], 1);
    }
    for (int i = (m4 << 2) + t; i < m; i += 256)
        atomicAdd(&cnt[col[start + i] >> 9], 1);
    __syncthreads();
    int c = cnt[t];
    base[t] = c ? atomicAdd(&bkt_cur[t], c) : 0;
    cnt[t] = 0;
    __syncthreads();
    for (int e = start + t; e < end; e += 256) {
        int cc = col[e];
        int bkt = cc >> 9;
        int pos = base[bkt] + atomicAdd(&cnt[bkt], 1);
        entries[pos] = row[e] | ((cc & (NB - 1)) << 17);
    }
}

// ---------- per-bucket CSR finalize: deg/dinv, shuffle scan, LDS scatter ----------
__global__ void __launch_bounds__(512) bfill_kernel(const int* __restrict__ entries,
                                                    const int* __restrict__ bkt_off,
                                                    int* __restrict__ csr_src,
                                                    int* __restrict__ csr_off,
                                                    float* __restrict__ dinv, int n, int E) {
    __shared__ int sdeg[NB];
    __shared__ int soff[NB];
    __shared__ int wtot[8];
    __shared__ int lsrc[CAP];
    int t = threadIdx.x;
    int wv = t >> 6, ln = t & 63;
    int b = blockIdx.x;
    int node0 = b << 9;
    int nn = min(NB, n - node0);
    int seg0 = bkt_off[b], seg1 = bkt_off[b + 1];
    int m = seg1 - seg0;
    sdeg[t] = 0;
    __syncthreads();
    for (int i = t; i < m; i += 512) atomicAdd(&sdeg[entries[seg0 + i] >> 17], 1);
    __syncthreads();
    int v = sdeg[t];
    int inc = v;
#pragma unroll
    for (int o = 1; o < 64; o <<= 1) {
        int u = __shfl_up(inc, o);
        if (ln >= o) inc += u;
    }
    if (ln == 63) wtot[wv] = inc;
    __syncthreads();
    if (wv == 0) {
        int tv = (ln < 8) ? wtot[ln] : 0;
        int ti = tv;
#pragma unroll
        for (int o = 1; o < 8; o <<= 1) {
            int u = __shfl_up(ti, o);
            if (ln >= o) ti += u;
        }
        if (ln < 8) wtot[ln] = ti - tv;  // exclusive wave base
    }
    __syncthreads();
    int excl = inc - v + wtot[wv];
    sdeg[t] = 0;     // reuse as cursor
    soff[t] = excl;
    __syncthreads();
    for (int i = t; i < m; i += 512) {
        int u = entries[seg0 + i];
        int l = u >> 17;
        int pos = soff[l] + atomicAdd(&sdeg[l], 1);
        lsrc[pos] = u & 0x1FFFF;
    }
    __syncthreads();
    for (int i = t; i < m; i += 512) csr_src[seg0 + i] = lsrc[i];
    if (t < nn) {
        csr_off[node0 + t] = seg0 + excl;
        dinv[node0 + t] = rsqrtf((float)(v + 1));  // +1 self-loop
    }
    if (b == gridDim.x - 1 && t == 0) csr_off[n] = E;
}

// ---------- f1 = bf16( dinv[r] * (x @ W1)[r] ) via MFMA ----------
__global__ void __launch_bounds__(256) xw_kernel(const float* __restrict__ x,
                                                 const float* __restrict__ W1,
                                                 const float* __restrict__ dinv,
                                                 unsigned short* __restrict__ f1,
                                                 int ntiles) {
    int lane = threadIdx.x & 63;
    int m = lane & 15;   // A row / B col / D col
    int q = lane >> 4;   // k-quad
    bf16x8 bfrag[8];
#pragma unroll
    for (int c = 0; c < 8; ++c) {
        const float* wp = W1 + (size_t)(c * 32 + q * 8) * HID + m;
#pragma unroll
        for (int j = 0; j < 8; ++j) bfrag[c][j] = (short)f2bf(wp[(size_t)j * HID]);
    }
    int wid = (blockIdx.x * 256 + threadIdx.x) >> 6;
    if (wid >= ntiles) return;
    int r0 = wid << 4;
    const float* xrow = x + (size_t)(r0 + m) * F_IN + q * 8;
    f32x4 acc = {0.f, 0.f, 0.f, 0.f};
#pragma unroll
    for (int c = 0; c < 8; ++c) {
        float4 v0 = *(const float4*)(xrow + c * 32);
        float4 v1 = *(const float4*)(xrow + c * 32 + 4);
        bf16x8 afrag;
        afrag[0] = (short)f2bf(v0.x);
        afrag[1] = (short)f2bf(v0.y);
        afrag[2] = (short)f2bf(v0.z);
        afrag[3] = (short)f2bf(v0.w);
        afrag[4] = (short)f2bf(v1.x);
        afrag[5] = (short)f2bf(v1.y);
        afrag[6] = (short)f2bf(v1.z);
        afrag[7] = (short)f2bf(v1.w);
        acc = __builtin_amdgcn_mfma_f32_16x16x32_bf16(afrag, bfrag[c], acc, 0, 0, 0);
    }
#pragma unroll
    for (int i = 0; i < 4; ++i) {
        int r = r0 + q * 4 + i;
        f1[(size_t)r * HID + m] = f2bf(dinv[r] * acc[i]);
    }
}

// ---------- layer-1 aggregation: 32 edge-slots x 2 lanes (uint4 loads) ----------
// feat rows are premultiplied p[v]=dinv[v]*xw1[v], 32B = 2 x uint4 halves.
__global__ void __launch_bounds__(256) agg1_kernel(const uint4* __restrict__ feat,
                                                   const float* __restrict__ dinv,
                                                   const int* __restrict__ csr_off,
                                                   const int* __restrict__ csr_src,
                                                   const float* __restrict__ b1,
                                                   uint4* __restrict__ f2, int n) {
    int wid = (blockIdx.x * 256 + threadIdx.x) >> 6;
    if (wid >= n) return;
    int lane = threadIdx.x & 63;
    int j = lane & 1, s = lane >> 1;   // 32 edges in flight x half-row per lane
    int start = csr_off[wid], end = csr_off[wid + 1];
    float a[8] = {0.f, 0.f, 0.f, 0.f, 0.f, 0.f, 0.f, 0.f};
    for (int ei = start + s; ei < end; ei += 32) {
        uint4 u = feat[csr_src[ei] * 2 + j];
        a[0] += bf_lo(u.x); a[1] += bf_hi(u.x);
        a[2] += bf_lo(u.y); a[3] += bf_hi(u.y);
        a[4] += bf_lo(u.z); a[5] += bf_hi(u.z);
        a[6] += bf_lo(u.w); a[7] += bf_hi(u.w);
    }
    if (s == 0) {  // self-loop, once per parity
        uint4 u = feat[wid * 2 + j];
        a[0] += bf_lo(u.x); a[1] += bf_hi(u.x);
        a[2] += bf_lo(u.y); a[3] += bf_hi(u.y);
        a[4] += bf_lo(u.z); a[5] += bf_hi(u.z);
        a[6] += bf_lo(u.w); a[7] += bf_hi(u.w);
    }
#pragma unroll
    for (int m = 2; m < 64; m <<= 1) {
#pragma unroll
        for (int k = 0; k < 8; ++k) a[k] += __shfl_xor(a[k], m);
    }
    if (lane < 2) {   // even lane: features 0-7, odd: 8-15
        float dc = dinv[wid];
        float4 c0 = *(const float4*)(b1 + j * 8);
        float4 c1 = *(const float4*)(b1 + j * 8 + 4);
        float v0 = fmaxf(dc * a[0] + c0.x, 0.f);
        float v1 = fmaxf(dc * a[1] + c0.y, 0.f);
        float v2 = fmaxf(dc * a[2] + c0.z, 0.f);
        float v3 = fmaxf(dc * a[3] + c0.w, 0.f);
        float v4 = fmaxf(dc * a[4] + c1.x, 0.f);
        float v5 = fmaxf(dc * a[5] + c1.y, 0.f);
        float v6 = fmaxf(dc * a[6] + c1.z, 0.f);
        float v7 = fmaxf(dc * a[7] + c1.w, 0.f);
        uint4 o;
        o.x = pack_bf(dc * v0, dc * v1);
        o.y = pack_bf(dc * v2, dc * v3);
        o.z = pack_bf(dc * v4, dc * v5);
        o.w = pack_bf(dc * v6, dc * v7);
        f2[wid * 2 + j] = o;
    }
}

// ---------- fused layer-2 aggregation + W2 matvec + log_softmax ----------
__global__ void __launch_bounds__(256) agg2out_kernel(const uint4* __restrict__ feat,
                                                      const float* __restrict__ dinv,
                                                      const int* __restrict__ csr_off,
                                                      const int* __restrict__ csr_src,
                                                      const float* __restrict__ W2,
                                                      const float* __restrict__ b2,
                                                      float* __restrict__ out, int n) {
    __shared__ float W2s[HID * NCLS];
    __shared__ float b2s[NCLS];
    for (int i = threadIdx.x; i < HID * NCLS; i += 256) W2s[i] = W2[i];
    if (threadIdx.x < NCLS) b2s[threadIdx.x] = b2[threadIdx.x];
    __syncthreads();
    int wid = (blockIdx.x * 256 + threadIdx.x) >> 6;
    if (wid >= n) return;
    int lane = threadIdx.x & 63;
    int j = lane & 1, s = lane >> 1;
    int start = csr_off[wid], end = csr_off[wid + 1];
    float a[8] = {0.f, 0.f, 0.f, 0.f, 0.f, 0.f, 0.f, 0.f};
    for (int ei = start + s; ei < end; ei += 32) {
        uint4 u = feat[csr_src[ei] * 2 + j];
        a[0] += bf_lo(u.x); a[1] += bf_hi(u.x);
        a[2] += bf_lo(u.y); a[3] += bf_hi(u.y);
        a[4] += bf_lo(u.z); a[5] += bf_hi(u.z);
        a[6] += bf_lo(u.w); a[7] += bf_hi(u.w);
    }
    if (s == 0) {  // self-loop
        uint4 u = feat[wid * 2 + j];
        a[0] += bf_lo(u.x); a[1] += bf_hi(u.x);
        a[2] += bf_lo(u.y); a[3] += bf_hi(u.y);
        a[4] += bf_lo(u.z); a[5] += bf_hi(u.z);
        a[6] += bf_lo(u.w); a[7] += bf_hi(u.w);
    }
#pragma unroll
    for (int m = 2; m < 64; m <<= 1) {
#pragma unroll
        for (int k = 0; k < 8; ++k) a[k] += __shfl_xor(a[k], m);
    }
    float dc = dinv[wid];
#pragma unroll
    for (int k = 0; k < 8; ++k) a[k] *= dc;
    float z = (lane < NCLS) ? b2s[lane] : 0.f;
#pragma unroll
    for (int k = 0; k < 8; ++k) {
        float e0 = __shfl(a[k], 0);   // feature k   (even-lane class)
        float e1 = __shfl(a[k], 1);   // feature 8+k (odd-lane class)
        if (lane < NCLS) {
            z += e0 * W2s[k * NCLS + lane];
            z += e1 * W2s[(8 + k) * NCLS + lane];
        }
    }
    float zz = (lane < NCLS) ? z : -INFINITY;
#pragma unroll
    for (int off = 1; off < 64; off <<= 1) zz = fmaxf(zz, __shfl_xor(zz, off));
    float es = (lane < NCLS) ? __expf(z - zz) : 0.f;
#pragma unroll
    for (int off = 1; off < 64; off <<= 1) es += __shfl_xor(es, off);
    float lse = zz + __logf(es);
    if (lane < NCLS) out[(size_t)wid * NCLS + lane] = z - lse;
}

extern "C" void kernel_launch(void* const* d_in, const int* in_sizes, int n_in,
                              void* d_out, int out_size, void* d_ws, size_t ws_size,
                              hipStream_t stream) {
    const float* x   = (const float*)d_in[0];
    const int*   ei  = (const int*)d_in[1];   // int32 indices from harness
    const float* W1  = (const float*)d_in[2];
    const float* b1  = (const float*)d_in[3];
    const float* W2  = (const float*)d_in[4];
    const float* b2  = (const float*)d_in[5];
    float*       out = (float*)d_out;

    int n = in_sizes[0] / F_IN;   // 100000 (< 2^17 for packing)
    int E = in_sizes[1] / 2;      // 3200000
    const int* rowp = ei;         // sources
    const int* colp = ei + E;     // targets
    int K = cdiv(n, NB);          // 196 buckets

    char* p = (char*)d_ws;
    auto alloc = [&](size_t bytes) {
        char* q = p;
        p += (bytes + 255) & ~(size_t)255;
        return q;
    };
    int*   bkt_cnt = (int*)  alloc((size_t)K * 4);
    int*   bkt_off = (int*)  alloc(((size_t)K + 1) * 4);
    int*   bkt_cur = (int*)  alloc((size_t)K * 4);
    int*   csr_off = (int*)  alloc(((size_t)n + 1) * 4);
    int*   csr_src = (int*)  alloc((size_t)E * 4);
    float* dinv    = (float*)alloc((size_t)n * 4);
    size_t fbytes = (size_t)n * HID * 2;
    char* region = alloc((size_t)E * 4 > 2 * fbytes ? (size_t)E * 4 : 2 * fbytes);
    int*            entries = (int*)region;
    unsigned short* f1      = (unsigned short*)region;
    uint4*          f2      = (uint4*)(region + fbytes);

    hipMemsetAsync(bkt_cnt, 0, (size_t)K * 4, stream);
    bcount_kernel<<<1024, 256, 0, stream>>>(colp, bkt_cnt, E, K);
    bscan_kernel<<<1, 256, 0, stream>>>(bkt_cnt, bkt_off, bkt_cur, K);
    bscatter_kernel<<<cdiv(E, SPAN), 256, 0, stream>>>(rowp, colp, bkt_cur, entries, E);
    bfill_kernel<<<K, 512, 0, stream>>>(entries, bkt_off, csr_src, csr_off, dinv, n, E);

    int ntiles = n >> 4;  // 6250 (n divisible by 16)
    xw_kernel<<<cdiv(ntiles, 4), 256, 0, stream>>>(x, W1, dinv, f1, ntiles);
    agg1_kernel<<<cdiv(n, 4), 256, 0, stream>>>((const uint4*)f1, dinv, csr_off, csr_src, b1, f2, n);
    agg2out_kernel<<<cdiv(n, 4), 256, 0, stream>>>(f2, dinv, csr_off, csr_src, W2, b2, out, n);
}

// Round 8
// 377.666 us; speedup vs baseline: 1.0675x; 1.0675x over previous
//
#include <hip/hip_runtime.h>

#define F_IN 256
#define HID  16
#define NCLS 40
#define NB   512      // nodes per bucket (dest >> 9)
#define CAP  18944    // max edges per bucket (mean 16.3K + 20 sigma); 74 KB -> 2 blocks/CU
#define SPAN 8192     // edges per bscatter block

static inline int cdiv(int a, int b) { return (a + b - 1) / b; }

typedef short bf16x8 __attribute__((ext_vector_type(8)));
typedef float f32x4  __attribute__((ext_vector_type(4)));

// ---------- bf16 helpers (top 16 bits of fp32, RNE) ----------
__device__ __forceinline__ float bf_lo(unsigned int u) { return __uint_as_float(u << 16); }
__device__ __forceinline__ float bf_hi(unsigned int u) { return __uint_as_float(u & 0xFFFF0000u); }
__device__ __forceinline__ unsigned short f2bf(float a) {
    unsigned int u = __float_as_uint(a);
    return (unsigned short)((u + 0x7FFFu + ((u >> 16) & 1u)) >> 16);
}
__device__ __forceinline__ unsigned int pack_bf(float a, float b) {
    return (unsigned int)f2bf(a) | ((unsigned int)f2bf(b) << 16);
}

// ---------- per-bucket edge counts (LDS hist -> few global atomics) ----------
__global__ void __launch_bounds__(256) bcount_kernel(const int* __restrict__ col,
                                                     int* __restrict__ bkt_cnt, int E, int K) {
    __shared__ int h[256];
    int t = threadIdx.x;
    h[t] = 0;
    __syncthreads();
    int E4 = E >> 2;
    const int4* c4 = (const int4*)col;
    for (int e = blockIdx.x * 256 + t; e < E4; e += gridDim.x * 256) {
        int4 v = c4[e];
        atomicAdd(&h[v.x >> 9], 1);
        atomicAdd(&h[v.y >> 9], 1);
        atomicAdd(&h[v.z >> 9], 1);
        atomicAdd(&h[v.w >> 9], 1);
    }
    for (int e = (E4 << 2) + blockIdx.x * 256 + t; e < E; e += gridDim.x * 256)
        atomicAdd(&h[col[e] >> 9], 1);
    __syncthreads();
    if (t < K && h[t]) atomicAdd(&bkt_cnt[t], h[t]);
}

// ---------- exclusive scan of bucket counts (K <= 256), init cursors ----------
__global__ void __launch_bounds__(256) bscan_kernel(const int* __restrict__ bkt_cnt,
                                                    int* __restrict__ bkt_off,
                                                    int* __restrict__ bkt_cur, int K) {
    __shared__ int s[256];
    int t = threadIdx.x;
    int v = (t < K) ? bkt_cnt[t] : 0;
    s[t] = v;
    __syncthreads();
    for (int off = 1; off < 256; off <<= 1) {
        int x = (t >= off) ? s[t - off] : 0;
        __syncthreads();
        s[t] += x;
        __syncthreads();
    }
    int excl = s[t] - v;
    if (t < K) { bkt_off[t] = excl; bkt_cur[t] = excl; }
    if (t == K - 1) bkt_off[K] = excl + v;
}

// ---------- bucketed scatter: runs of packed entries per (block,bucket) ----------
// entry = row | (local_dest << 17); row < 2^17, local_dest < 512
__global__ void __launch_bounds__(256) bscatter_kernel(const int* __restrict__ row,
                                                       const int* __restrict__ col,
                                                       int* __restrict__ bkt_cur,
                                                       int* __restrict__ entries, int E) {
    __shared__ int cnt[256];
    __shared__ int base[256];
    int t = threadIdx.x;
    int start = blockIdx.x * SPAN;
    int end = min(start + SPAN, E);
    cnt[t] = 0;
    __syncthreads();
    int m = end - start;
    int m4 = m >> 2;
    const int4* c4 = (const int4*)(col + start);
    for (int i = t; i < m4; i += 256) {
        int4 v = c4[i];
        atomicAdd(&cnt[v.x >> 9], 1);
        atomicAdd(&cnt[v.y >> 9], 1);
        atomicAdd(&cnt[v.z >> 9], 1);
        atomicAdd(&cnt[v.w >> 9], 1);
    }
    for (int i = (m4 << 2) + t; i < m; i += 256)
        atomicAdd(&cnt[col[start + i] >> 9], 1);
    __syncthreads();
    int c = cnt[t];
    base[t] = c ? atomicAdd(&bkt_cur[t], c) : 0;
    cnt[t] = 0;
    __syncthreads();
    for (int e = start + t; e < end; e += 256) {
        int cc = col[e];
        int bkt = cc >> 9;
        int pos = base[bkt] + atomicAdd(&cnt[bkt], 1);
        entries[pos] = row[e] | ((cc & (NB - 1)) << 17);
    }
}

// ---------- per-bucket CSR finalize: deg/dinv, shuffle scan, LDS scatter ----------
__global__ void __launch_bounds__(512) bfill_kernel(const int* __restrict__ entries,
                                                    const int* __restrict__ bkt_off,
                                                    int* __restrict__ csr_src,
                                                    int* __restrict__ csr_off,
                                                    float* __restrict__ dinv, int n, int E) {
    __shared__ int sdeg[NB];
    __shared__ int soff[NB];
    __shared__ int wtot[8];
    __shared__ int lsrc[CAP];
    int t = threadIdx.x;
    int wv = t >> 6, ln = t & 63;
    int b = blockIdx.x;
    int node0 = b << 9;
    int nn = min(NB, n - node0);
    int seg0 = bkt_off[b], seg1 = bkt_off[b + 1];
    int m = seg1 - seg0;
    sdeg[t] = 0;
    __syncthreads();
    for (int i = t; i < m; i += 512) atomicAdd(&sdeg[entries[seg0 + i] >> 17], 1);
    __syncthreads();
    int v = sdeg[t];
    int inc = v;
#pragma unroll
    for (int o = 1; o < 64; o <<= 1) {
        int u = __shfl_up(inc, o);
        if (ln >= o) inc += u;
    }
    if (ln == 63) wtot[wv] = inc;
    __syncthreads();
    if (wv == 0) {
        int tv = (ln < 8) ? wtot[ln] : 0;
        int ti = tv;
#pragma unroll
        for (int o = 1; o < 8; o <<= 1) {
            int u = __shfl_up(ti, o);
            if (ln >= o) ti += u;
        }
        if (ln < 8) wtot[ln] = ti - tv;  // exclusive wave base
    }
    __syncthreads();
    int excl = inc - v + wtot[wv];
    sdeg[t] = 0;     // reuse as cursor
    soff[t] = excl;
    __syncthreads();
    for (int i = t; i < m; i += 512) {
        int u = entries[seg0 + i];
        int l = u >> 17;
        int pos = soff[l] + atomicAdd(&sdeg[l], 1);
        lsrc[pos] = u & 0x1FFFF;
    }
    __syncthreads();
    for (int i = t; i < m; i += 512) csr_src[seg0 + i] = lsrc[i];
    if (t < nn) {
        csr_off[node0 + t] = seg0 + excl;
        dinv[node0 + t] = rsqrtf((float)(v + 1));  // +1 self-loop
    }
    if (b == gridDim.x - 1 && t == 0) csr_off[n] = E;
}

// ---------- f1 = bf16( dinv[r] * (x @ W1)[r] ) via MFMA ----------
__global__ void __launch_bounds__(256) xw_kernel(const float* __restrict__ x,
                                                 const float* __restrict__ W1,
                                                 const float* __restrict__ dinv,
                                                 unsigned short* __restrict__ f1,
                                                 int ntiles) {
    int lane = threadIdx.x & 63;
    int m = lane & 15;   // A row / B col / D col
    int q = lane >> 4;   // k-quad
    bf16x8 bfrag[8];
#pragma unroll
    for (int c = 0; c < 8; ++c) {
        const float* wp = W1 + (size_t)(c * 32 + q * 8) * HID + m;
#pragma unroll
        for (int j = 0; j < 8; ++j) bfrag[c][j] = (short)f2bf(wp[(size_t)j * HID]);
    }
    int wid = (blockIdx.x * 256 + threadIdx.x) >> 6;
    if (wid >= ntiles) return;
    int r0 = wid << 4;
    const float* xrow = x + (size_t)(r0 + m) * F_IN + q * 8;
    f32x4 acc = {0.f, 0.f, 0.f, 0.f};
#pragma unroll
    for (int c = 0; c < 8; ++c) {
        float4 v0 = *(const float4*)(xrow + c * 32);
        float4 v1 = *(const float4*)(xrow + c * 32 + 4);
        bf16x8 afrag;
        afrag[0] = (short)f2bf(v0.x);
        afrag[1] = (short)f2bf(v0.y);
        afrag[2] = (short)f2bf(v0.z);
        afrag[3] = (short)f2bf(v0.w);
        afrag[4] = (short)f2bf(v1.x);
        afrag[5] = (short)f2bf(v1.y);
        afrag[6] = (short)f2bf(v1.z);
        afrag[7] = (short)f2bf(v1.w);
        acc = __builtin_amdgcn_mfma_f32_16x16x32_bf16(afrag, bfrag[c], acc, 0, 0, 0);
    }
#pragma unroll
    for (int i = 0; i < 4; ++i) {
        int r = r0 + q * 4 + i;
        f1[(size_t)r * HID + m] = f2bf(dinv[r] * acc[i]);
    }
}

// ---------- layer-1 aggregation: 8 edge-slots x 8 j-lanes, 4-way pipelined ----------
__global__ void __launch_bounds__(256) agg1_kernel(const unsigned int* __restrict__ feat,
                                                   const float* __restrict__ dinv,
                                                   const int* __restrict__ csr_off,
                                                   const int* __restrict__ csr_src,
                                                   const float* __restrict__ b1,
                                                   unsigned int* __restrict__ f2, int n) {
    int wid = (blockIdx.x * 256 + threadIdx.x) >> 6;
    if (wid >= n) return;
    int lane = threadIdx.x & 63;
    int j = lane & 7, s = lane >> 3;
    int start = csr_off[wid], end = csr_off[wid + 1];
    float a0 = 0.f, a1 = 0.f;
    int ei = start + s;
    // 4-way software pipeline: batch 4 independent index loads, then 4 gathers
    for (; ei + 24 < end; ei += 32) {
        int i0 = csr_src[ei];
        int i1 = csr_src[ei + 8];
        int i2 = csr_src[ei + 16];
        int i3 = csr_src[ei + 24];
        unsigned int u0 = feat[(size_t)i0 * 8 + j];
        unsigned int u1 = feat[(size_t)i1 * 8 + j];
        unsigned int u2 = feat[(size_t)i2 * 8 + j];
        unsigned int u3 = feat[(size_t)i3 * 8 + j];
        a0 += bf_lo(u0); a1 += bf_hi(u0);
        a0 += bf_lo(u1); a1 += bf_hi(u1);
        a0 += bf_lo(u2); a1 += bf_hi(u2);
        a0 += bf_lo(u3); a1 += bf_hi(u3);
    }
    for (; ei < end; ei += 8) {
        unsigned int u = feat[(size_t)csr_src[ei] * 8 + j];
        a0 += bf_lo(u); a1 += bf_hi(u);
    }
    a0 += __shfl_xor(a0, 8);  a1 += __shfl_xor(a1, 8);
    a0 += __shfl_xor(a0, 16); a1 += __shfl_xor(a1, 16);
    a0 += __shfl_xor(a0, 32); a1 += __shfl_xor(a1, 32);
    if (lane < 8) {
        unsigned int us = feat[(size_t)wid * 8 + j];
        float dc = dinv[wid];
        float v0 = fmaxf(dc * (a0 + bf_lo(us)) + b1[2 * j],     0.f);
        float v1 = fmaxf(dc * (a1 + bf_hi(us)) + b1[2 * j + 1], 0.f);
        f2[(size_t)wid * 8 + j] = pack_bf(dc * v0, dc * v1);
    }
}

// ---------- fused layer-2 aggregation + W2 matvec + log_softmax ----------
__global__ void __launch_bounds__(256) agg2out_kernel(const unsigned int* __restrict__ feat,
                                                      const float* __restrict__ dinv,
                                                      const int* __restrict__ csr_off,
                                                      const int* __restrict__ csr_src,
                                                      const float* __restrict__ W2,
                                                      const float* __restrict__ b2,
                                                      float* __restrict__ out, int n) {
    __shared__ float W2s[HID * NCLS];
    __shared__ float b2s[NCLS];
    for (int i = threadIdx.x; i < HID * NCLS; i += 256) W2s[i] = W2[i];
    if (threadIdx.x < NCLS) b2s[threadIdx.x] = b2[threadIdx.x];
    __syncthreads();
    int wid = (blockIdx.x * 256 + threadIdx.x) >> 6;
    if (wid >= n) return;
    int lane = threadIdx.x & 63;
    int j = lane & 7, s = lane >> 3;
    int start = csr_off[wid], end = csr_off[wid + 1];
    float a0 = 0.f, a1 = 0.f;
    int ei = start + s;
    for (; ei + 24 < end; ei += 32) {
        int i0 = csr_src[ei];
        int i1 = csr_src[ei + 8];
        int i2 = csr_src[ei + 16];
        int i3 = csr_src[ei + 24];
        unsigned int u0 = feat[(size_t)i0 * 8 + j];
        unsigned int u1 = feat[(size_t)i1 * 8 + j];
        unsigned int u2 = feat[(size_t)i2 * 8 + j];
        unsigned int u3 = feat[(size_t)i3 * 8 + j];
        a0 += bf_lo(u0); a1 += bf_hi(u0);
        a0 += bf_lo(u1); a1 += bf_hi(u1);
        a0 += bf_lo(u2); a1 += bf_hi(u2);
        a0 += bf_lo(u3); a1 += bf_hi(u3);
    }
    for (; ei < end; ei += 8) {
        unsigned int u = feat[(size_t)csr_src[ei] * 8 + j];
        a0 += bf_lo(u); a1 += bf_hi(u);
    }
    if (s == 0) {  // self-loop, counted once
        unsigned int us = feat[(size_t)wid * 8 + j];
        a0 += bf_lo(us); a1 += bf_hi(us);
    }
    a0 += __shfl_xor(a0, 8);  a1 += __shfl_xor(a1, 8);
    a0 += __shfl_xor(a0, 16); a1 += __shfl_xor(a1, 16);
    a0 += __shfl_xor(a0, 32); a1 += __shfl_xor(a1, 32);
    float dc = dinv[wid];
    float z = (lane < NCLS) ? b2s[lane] : 0.f;
#pragma unroll
    for (int q = 0; q < 8; ++q) {
        float e0 = dc * __shfl(a0, q);
        float e1 = dc * __shfl(a1, q);
        if (lane < NCLS) {
            z += e0 * W2s[(2 * q)     * NCLS + lane];
            z += e1 * W2s[(2 * q + 1) * NCLS + lane];
        }
    }
    float zz = (lane < NCLS) ? z : -INFINITY;
#pragma unroll
    for (int off = 1; off < 64; off <<= 1) zz = fmaxf(zz, __shfl_xor(zz, off));
    float es = (lane < NCLS) ? __expf(z - zz) : 0.f;
#pragma unroll
    for (int off = 1; off < 64; off <<= 1) es += __shfl_xor(es, off);
    float lse = zz + __logf(es);
    if (lane < NCLS) out[(size_t)wid * NCLS + lane] = z - lse;
}

extern "C" void kernel_launch(void* const* d_in, const int* in_sizes, int n_in,
                              void* d_out, int out_size, void* d_ws, size_t ws_size,
                              hipStream_t stream) {
    const float* x   = (const float*)d_in[0];
    const int*   ei  = (const int*)d_in[1];   // int32 indices from harness
    const float* W1  = (const float*)d_in[2];
    const float* b1  = (const float*)d_in[3];
    const float* W2  = (const float*)d_in[4];
    const float* b2  = (const float*)d_in[5];
    float*       out = (float*)d_out;

    int n = in_sizes[0] / F_IN;   // 100000 (< 2^17 for packing)
    int E = in_sizes[1] / 2;      // 3200000
    const int* rowp = ei;         // sources
    const int* colp = ei + E;     // targets
    int K = cdiv(n, NB);          // 196 buckets

    char* p = (char*)d_ws;
    auto alloc = [&](size_t bytes) {
        char* q = p;
        p += (bytes + 255) & ~(size_t)255;
        return q;
    };
    int*   bkt_cnt = (int*)  alloc((size_t)K * 4);
    int*   bkt_off = (int*)  alloc(((size_t)K + 1) * 4);
    int*   bkt_cur = (int*)  alloc((size_t)K * 4);
    int*   csr_off = (int*)  alloc(((size_t)n + 1) * 4);
    int*   csr_src = (int*)  alloc((size_t)E * 4);
    float* dinv    = (float*)alloc((size_t)n * 4);
    size_t fbytes = (size_t)n * HID * 2;
    char* region = alloc((size_t)E * 4 > 2 * fbytes ? (size_t)E * 4 : 2 * fbytes);
    int*            entries = (int*)region;
    unsigned short* f1      = (unsigned short*)region;
    unsigned int*   f2      = (unsigned int*)(region + fbytes);

    hipMemsetAsync(bkt_cnt, 0, (size_t)K * 4, stream);
    bcount_kernel<<<1024, 256, 0, stream>>>(colp, bkt_cnt, E, K);
    bscan_kernel<<<1, 256, 0, stream>>>(bkt_cnt, bkt_off, bkt_cur, K);
    bscatter_kernel<<<cdiv(E, SPAN), 256, 0, stream>>>(rowp, colp, bkt_cur, entries, E);
    bfill_kernel<<<K, 512, 0, stream>>>(entries, bkt_off, csr_src, csr_off, dinv, n, E);

    int ntiles = n >> 4;  // 6250 (n divisible by 16)
    xw_kernel<<<cdiv(ntiles, 4), 256, 0, stream>>>(x, W1, dinv, f1, ntiles);
    agg1_kernel<<<cdiv(n, 4), 256, 0, stream>>>((const unsigned int*)f1, dinv, csr_off, csr_src, b1, f2, n);
    agg2out_kernel<<<cdiv(n, 4), 256, 0, stream>>>(f2, dinv, csr_off, csr_src, W2, b2, out, n);
}